// Round 2
// baseline (432.266 us; speedup 1.0000x reference)
//
#include <hip/hip_runtime.h>
#include <cstdint>
#include <cstddef>

#define N_NODES 8192
#define INF 512
#define OUTF 256
#define SPLITK 4
#define LOG_SPLITK 2
#define MSLICE (N_NODES / SPLITK)  // 2048
#define BN2 128                    // gemm2 n-tile
#define KT2 (MSLICE / 64)          // 32 k-iterations in gemm2

typedef _Float16 f16;
typedef _Float16 f16x8 __attribute__((ext_vector_type(8)));
typedef _Float16 f16x4 __attribute__((ext_vector_type(4)));
typedef float f32x4 __attribute__((ext_vector_type(4)));

__device__ __forceinline__ void async_copy16(void* lds_dst, const void* g_src) {
  __builtin_amdgcn_global_load_lds(
      (const __attribute__((address_space(1))) void*)g_src,
      (__attribute__((address_space(3))) void*)lds_dst,
      16, 0, 0);
}

__device__ __forceinline__ float elu(float x) { return x > 0.f ? x : expm1f(x); }

// -------- prep: W [512][256] fp32 -> WhT [256][512] f16 (512 KB, tiny) -----
__global__ __launch_bounds__(256) void prep_w(const float* __restrict__ W,
                                              f16* __restrict__ WhT) {
  const int idx = blockIdx.x * 256 + threadIdx.x;  // 131072
  const int o = idx >> 9, i = idx & 511;
  WhT[idx] = (f16)W[i * OUTF + o];  // write coalesced; read via L2 (512 KB)
}

// -------- gemm1: supT[o][m] = sum_k WhT[o][k] * X[m][k]  (X cast fused) ----
// Tile 64o x 64m, BK=64, 8 iters. Double-buffered LDS, prefetch-next:
// DMA(kt+1) + X-loads(kt+1) issued BEFORE compute(kt); one barrier per kt.
__global__ __launch_bounds__(256) void gemm1(const f16* __restrict__ WhT,
                                             const float* __restrict__ X,
                                             f16* __restrict__ supT) {
  __shared__ __align__(16) f16 Asm[2][64 * 64];  // WhT tile, XOR chunk-swizzled
  __shared__ __align__(16) f16 Bsm[2][64 * 64];  // X tile (f16), XOR-swizzled
  const int t = threadIdx.x;
  const int wave = t >> 6, lane = t & 63;
  const int q = lane >> 4, r = lane & 15;
  const int lrow = lane >> 3, lchunk = lane & 7;
  const int o0 = blockIdx.x * 64, m0 = blockIdx.y * 64;

  f32x4 acc[4];
#pragma unroll
  for (int i = 0; i < 4; ++i) acc[i] = (f32x4){0.f, 0.f, 0.f, 0.f};

  const int b_row = t >> 2;       // m' 0..63
  const int b_c0 = (t & 3) * 2;   // first of 2 logical chunks
  const float* xptr = X + (size_t)(m0 + b_row) * INF + (t & 3) * 16;

  f32x4 xv[4];

  auto issueA = [&](int kt, int buf) {
#pragma unroll
    for (int op = 0; op < 2; ++op) {
      const int row = (wave * 2 + op) * 8 + lrow;
      const f16* src = WhT + (size_t)(o0 + row) * INF + kt * 64 + (lchunk ^ lrow) * 8;
      async_copy16(&Asm[buf][(wave * 2 + op) * 512], src);
    }
  };
  auto loadB = [&](int kt) {
    const float* xp = xptr + kt * 64;
    xv[0] = *(const f32x4*)(xp + 0);
    xv[1] = *(const f32x4*)(xp + 4);
    xv[2] = *(const f32x4*)(xp + 8);
    xv[3] = *(const f32x4*)(xp + 12);
  };
  auto writeB = [&](int buf) {
    f16x8 h0, h1;
#pragma unroll
    for (int u = 0; u < 4; ++u) {
      h0[u] = (f16)xv[0][u];
      h0[4 + u] = (f16)xv[1][u];
      h1[u] = (f16)xv[2][u];
      h1[4 + u] = (f16)xv[3][u];
    }
    *(f16x8*)&Bsm[buf][b_row * 64 + ((b_c0 ^ (b_row & 7)) * 8)] = h0;
    *(f16x8*)&Bsm[buf][b_row * 64 + (((b_c0 + 1) ^ (b_row & 7)) * 8)] = h1;
  };

  // prologue: stage kt=0 into buffer 0
  issueA(0, 0);
  loadB(0);
  writeB(0);
  __syncthreads();

  for (int kt = 0; kt < 8; ++kt) {
    const int c = kt & 1, o = c ^ 1;
    if (kt + 1 < 8) {
      issueA(kt + 1, o);   // DMA flies across the whole compute phase
      loadB(kt + 1);       // X loads fly across the whole compute phase
    }
#pragma unroll
    for (int s = 0; s < 2; ++s) {
      const int pc = ((s * 4 + q) ^ (r & 7)) * 8;
      f16x8 af[4];
#pragma unroll
      for (int i = 0; i < 4; ++i) af[i] = *(const f16x8*)&Asm[c][(i * 16 + r) * 64 + pc];
      const f16x8 bf = *(const f16x8*)&Bsm[c][(wave * 16 + r) * 64 + pc];
#pragma unroll
      for (int i = 0; i < 4; ++i)
        acc[i] = __builtin_amdgcn_mfma_f32_16x16x32_f16(af[i], bf, acc[i], 0, 0, 0);
    }
    if (kt + 1 < 8) writeB(o);  // after compute's ds_reads; different buffer
    __syncthreads();            // drains DMA(kt+1) + writes; swap
  }
  // C/D: row(o)=q*4+g, col(m)=r
  const int m = m0 + wave * 16 + r;
#pragma unroll
  for (int i = 0; i < 4; ++i)
#pragma unroll
    for (int g = 0; g < 4; ++g)
      supT[(size_t)(o0 + i * 16 + q * 4 + g) * N_NODES + m] = (f16)acc[i][g];
}

// -------- gemm2: P16[y][n][o] = sum_{m in slice y} adj[n][m]^2 * supT[o][m] --
// 128n x 256o tile, BK=64, split-K=4. 512 threads (8 waves as 2n x 4o).
// Fully double-buffered LDS (96 KB, 1 block/CU; grid 256 = 1/CU).
// Prefetch-next structure: one barrier per kt, loads hidden under MFMA.
// y = wg&3: under round-robin dispatch XCD k serves slice (k mod 4) only,
// so its 1 MB supT slice stays L2-resident against the adj stream.
template <bool ATOMIC>
__global__ __launch_bounds__(512) void gemm2(const float* __restrict__ adj,
                                             const f16* __restrict__ supT,
                                             f16* __restrict__ P16,
                                             float* __restrict__ outp) {
  __shared__ __align__(16) f16 Asm[2][BN2 * 64];  // adj^2 tiles (2 x 16 KB)
  __shared__ __align__(16) f16 Bsm[2][256 * 64];  // supT tiles (2 x 32 KB)
  const int t = threadIdx.x;
  const int wave = t >> 6, lane = t & 63;
  const int q = lane >> 4, r = lane & 15;
  const int wn = wave >> 2, wo = wave & 3;  // wave tile: 64n x 64o
  const int wg = blockIdx.x;
  const int y = wg & (SPLITK - 1);
  const int n0 = (wg >> LOG_SPLITK) * BN2;
  const size_t m_base = (size_t)y * MSLICE;

  f32x4 acc[4][4];
#pragma unroll
  for (int i = 0; i < 4; ++i)
#pragma unroll
    for (int j = 0; j < 4; ++j) acc[i][j] = (f32x4){0.f, 0.f, 0.f, 0.f};

  const int a_row = t >> 2;        // 0..127
  const int a_c0 = (t & 3) * 2;
  const float* aptr = adj + (size_t)(n0 + a_row) * N_NODES + m_base + (t & 3) * 16;
  const int b_o8 = lane >> 3;      // row within an 8-row copy group
  const int b_kb = lane & 7;

  f32x4 av[4];

  auto issueB = [&](int kt, int buf) {
#pragma unroll
    for (int j = 0; j < 4; ++j) {
      const int c = wave * 4 + j;          // 0..31 -> rows c*8..c*8+7
      const int o = c * 8 + b_o8;
      const int kb = b_kb ^ (o & 7);
      const f16* src = supT + (size_t)o * N_NODES + m_base + kt * 64 + kb * 8;
      async_copy16(&Bsm[buf][c * 8 * 64], src);
    }
  };
  auto loadA = [&](int kt) {
    const float* ap = aptr + kt * 64;
    av[0] = *(const f32x4*)(ap + 0);
    av[1] = *(const f32x4*)(ap + 4);
    av[2] = *(const f32x4*)(ap + 8);
    av[3] = *(const f32x4*)(ap + 12);
  };
  auto writeA = [&](int buf) {
    f16x8 h0, h1;
#pragma unroll
    for (int u = 0; u < 4; ++u) {
      h0[u] = (f16)(av[0][u] * av[0][u]);
      h0[4 + u] = (f16)(av[1][u] * av[1][u]);
      h1[u] = (f16)(av[2][u] * av[2][u]);
      h1[4 + u] = (f16)(av[3][u] * av[3][u]);
    }
    *(f16x8*)&Asm[buf][a_row * 64 + ((a_c0 ^ (a_row & 7)) * 8)] = h0;
    *(f16x8*)&Asm[buf][a_row * 64 + (((a_c0 + 1) ^ (a_row & 7)) * 8)] = h1;
  };

  // prologue: stage kt=0 into buffer 0
  issueB(0, 0);
  loadA(0);
  writeA(0);
  __syncthreads();

  for (int kt = 0; kt < KT2; ++kt) {
    const int cb = kt & 1, ob = cb ^ 1;
    if (kt + 1 < KT2) {
      issueB(kt + 1, ob);  // supT DMA flies under the MFMA phase
      loadA(kt + 1);       // adj loads fly under the MFMA phase
    }
#pragma unroll
    for (int s = 0; s < 2; ++s) {
      const int pc = ((s * 4 + q) ^ (r & 7)) * 8;
      f16x8 af[4], bf[4];
#pragma unroll
      for (int i = 0; i < 4; ++i)
        af[i] = *(const f16x8*)&Asm[cb][(wn * 64 + i * 16 + r) * 64 + pc];
#pragma unroll
      for (int j = 0; j < 4; ++j)
        bf[j] = *(const f16x8*)&Bsm[cb][(wo * 64 + j * 16 + r) * 64 + pc];
#pragma unroll
      for (int i = 0; i < 4; ++i)
#pragma unroll
        for (int j = 0; j < 4; ++j)
          acc[i][j] = __builtin_amdgcn_mfma_f32_16x16x32_f16(af[i], bf[j],
                                                             acc[i][j], 0, 0, 0);
    }
    if (kt + 1 < KT2) writeA(ob);  // square+cvt after compute; other buffer
    __syncthreads();               // single barrier per kt: drain + swap
  }
  if (ATOMIC) {
#pragma unroll
    for (int i = 0; i < 4; ++i)
#pragma unroll
      for (int g = 0; g < 4; ++g) {
        const int n = n0 + wn * 64 + i * 16 + q * 4 + g;
        float* orow = outp + (size_t)n * OUTF + wo * 64 + r;
#pragma unroll
        for (int j = 0; j < 4; ++j) atomicAdd(orow + j * 16, acc[i][j][g]);
      }
  } else {
    f16* base = P16 + (size_t)y * N_NODES * OUTF;
#pragma unroll
    for (int i = 0; i < 4; ++i)
#pragma unroll
      for (int g = 0; g < 4; ++g) {
        const int n = n0 + wn * 64 + i * 16 + q * 4 + g;
        f16* orow = base + (size_t)n * OUTF + wo * 64 + r;
#pragma unroll
        for (int j = 0; j < 4; ++j) orow[j * 16] = (f16)acc[i][j][g];
      }
  }
}

// -------- epilogue A: sum 4 f16 partial planes + bias + ELU (16B loads) ----
__global__ __launch_bounds__(256) void reduce_elu(const f16* __restrict__ P16,
                                                  const float* __restrict__ bias,
                                                  float* __restrict__ out) {
  const int idx = blockIdx.x * 256 + threadIdx.x;  // f16x8 index, 262144 total
  float s[8];
#pragma unroll
  for (int u = 0; u < 8; ++u) s[u] = 0.f;
#pragma unroll
  for (int y = 0; y < SPLITK; ++y) {
    const f16x8 h = ((const f16x8*)(P16 + (size_t)y * N_NODES * OUTF))[idx];
#pragma unroll
    for (int u = 0; u < 8; ++u) s[u] += (float)h[u];
  }
  const float* bp = bias + (idx & 31) * 8;
  f32x4 v0, v1;
#pragma unroll
  for (int u = 0; u < 4; ++u) {
    v0[u] = elu(s[u] + bp[u]);
    v1[u] = elu(s[4 + u] + bp[4 + u]);
  }
  ((f32x4*)out)[idx * 2 + 0] = v0;
  ((f32x4*)out)[idx * 2 + 1] = v1;
}

// -------- epilogue B (atomic fallback): in-place bias + ELU --------
__global__ __launch_bounds__(256) void bias_elu(float* __restrict__ out,
                                                const float* __restrict__ bias) {
  const int idx = blockIdx.x * 256 + threadIdx.x;
  f32x4 v = ((const f32x4*)out)[idx];
  const f32x4 b = ((const f32x4*)bias)[idx & 63];
#pragma unroll
  for (int u = 0; u < 4; ++u) v[u] = elu(v[u] + b[u]);
  ((f32x4*)out)[idx] = v;
}

extern "C" void kernel_launch(void* const* d_in, const int* in_sizes, int n_in,
                              void* d_out, int out_size, void* d_ws, size_t ws_size,
                              hipStream_t stream) {
  const float* X = (const float*)d_in[0];     // [8192, 512]
  const float* adj = (const float*)d_in[1];   // [8192, 8192]
  const float* W = (const float*)d_in[2];     // [512, 256]
  const float* bias = (const float*)d_in[3];  // [256]
  float* out = (float*)d_out;                 // [8192, 256] fp32

  char* ws = (char*)d_ws;
  f16* supT = (f16*)(ws + 0);           // 4 MB
  f16* WhT = (f16*)(ws + (4u << 20));   // 256 KB
  f16* P16 = (f16*)(ws + (8u << 20));   // 16 MB f16 partials (4 planes)
  const size_t need = (32u << 20);

  prep_w<<<INF * OUTF / 256, 256, 0, stream>>>(W, WhT);
  gemm1<<<dim3(OUTF / 64, N_NODES / 64), 256, 0, stream>>>(WhT, X, supT);
  if (ws_size >= need) {
    gemm2<false><<<dim3((N_NODES / BN2) * SPLITK), dim3(512), 0, stream>>>(adj, supT, P16, nullptr);
    reduce_elu<<<N_NODES * OUTF / 8 / 256, 256, 0, stream>>>(P16, bias, out);
  } else {
    hipMemsetAsync(d_out, 0, (size_t)out_size * sizeof(float), stream);
    gemm2<true><<<dim3((N_NODES / BN2) * SPLITK), dim3(512), 0, stream>>>(adj, supT, nullptr, out);
    bias_elu<<<N_NODES * OUTF / 4 / 256, 256, 0, stream>>>(out, bias);
  }
}

// Round 3
// 421.772 us; speedup vs baseline: 1.0249x; 1.0249x over previous
//
#include <hip/hip_runtime.h>
#include <cstdint>
#include <cstddef>

#define N_NODES 8192
#define INF 512
#define OUTF 256
#define SPLITK 8
#define LOG_SPLITK 3
#define MSLICE (N_NODES / SPLITK)  // 1024
#define BN2 128                    // gemm2 n-tile
#define KT2 (MSLICE / 64)          // 16 k-iterations in gemm2

typedef _Float16 f16;
typedef _Float16 f16x8 __attribute__((ext_vector_type(8)));
typedef _Float16 f16x4 __attribute__((ext_vector_type(4)));
typedef float f32x4 __attribute__((ext_vector_type(4)));

__device__ __forceinline__ void async_copy16(void* lds_dst, const void* g_src) {
  __builtin_amdgcn_global_load_lds(
      (const __attribute__((address_space(1))) void*)g_src,
      (__attribute__((address_space(3))) void*)lds_dst,
      16, 0, 0);
}

__device__ __forceinline__ float elu(float x) { return x > 0.f ? x : expm1f(x); }

// -------- prep: W [512][256] fp32 -> WhT [256][512] f16 (512 KB, tiny) -----
__global__ __launch_bounds__(256) void prep_w(const float* __restrict__ W,
                                              f16* __restrict__ WhT) {
  const int idx = blockIdx.x * 256 + threadIdx.x;  // 131072
  const int o = idx >> 9, i = idx & 511;
  WhT[idx] = (f16)W[i * OUTF + o];  // write coalesced; read via L2 (512 KB)
}

// -------- gemm1: supT[o][m] = sum_k WhT[o][k] * X[m][k]  (X cast fused) ----
// Tile 64o x 64m, BK=64, 8 iters. Double-buffered LDS, prefetch-next:
// DMA(kt+1) + X-loads(kt+1) issued BEFORE compute(kt); one barrier per kt.
// 32 KB LDS, 256 threads -> >=2 blocks/CU. Known-good from R2.
__global__ __launch_bounds__(256) void gemm1(const f16* __restrict__ WhT,
                                             const float* __restrict__ X,
                                             f16* __restrict__ supT) {
  __shared__ __align__(16) f16 Asm[2][64 * 64];  // WhT tile, XOR chunk-swizzled
  __shared__ __align__(16) f16 Bsm[2][64 * 64];  // X tile (f16), XOR-swizzled
  const int t = threadIdx.x;
  const int wave = t >> 6, lane = t & 63;
  const int q = lane >> 4, r = lane & 15;
  const int lrow = lane >> 3, lchunk = lane & 7;
  const int o0 = blockIdx.x * 64, m0 = blockIdx.y * 64;

  f32x4 acc[4];
#pragma unroll
  for (int i = 0; i < 4; ++i) acc[i] = (f32x4){0.f, 0.f, 0.f, 0.f};

  const int b_row = t >> 2;       // m' 0..63
  const int b_c0 = (t & 3) * 2;   // first of 2 logical chunks
  const float* xptr = X + (size_t)(m0 + b_row) * INF + (t & 3) * 16;

  f32x4 xv[4];

  auto issueA = [&](int kt, int buf) {
#pragma unroll
    for (int op = 0; op < 2; ++op) {
      const int row = (wave * 2 + op) * 8 + lrow;
      const f16* src = WhT + (size_t)(o0 + row) * INF + kt * 64 + (lchunk ^ lrow) * 8;
      async_copy16(&Asm[buf][(wave * 2 + op) * 512], src);
    }
  };
  auto loadB = [&](int kt) {
    const float* xp = xptr + kt * 64;
    xv[0] = *(const f32x4*)(xp + 0);
    xv[1] = *(const f32x4*)(xp + 4);
    xv[2] = *(const f32x4*)(xp + 8);
    xv[3] = *(const f32x4*)(xp + 12);
  };
  auto writeB = [&](int buf) {
    f16x8 h0, h1;
#pragma unroll
    for (int u = 0; u < 4; ++u) {
      h0[u] = (f16)xv[0][u];
      h0[4 + u] = (f16)xv[1][u];
      h1[u] = (f16)xv[2][u];
      h1[4 + u] = (f16)xv[3][u];
    }
    *(f16x8*)&Bsm[buf][b_row * 64 + ((b_c0 ^ (b_row & 7)) * 8)] = h0;
    *(f16x8*)&Bsm[buf][b_row * 64 + (((b_c0 + 1) ^ (b_row & 7)) * 8)] = h1;
  };

  // prologue: stage kt=0 into buffer 0
  issueA(0, 0);
  loadB(0);
  writeB(0);
  __syncthreads();

  for (int kt = 0; kt < 8; ++kt) {
    const int c = kt & 1, o = c ^ 1;
    if (kt + 1 < 8) {
      issueA(kt + 1, o);   // DMA flies across the whole compute phase
      loadB(kt + 1);       // X loads fly across the whole compute phase
    }
#pragma unroll
    for (int s = 0; s < 2; ++s) {
      const int pc = ((s * 4 + q) ^ (r & 7)) * 8;
      f16x8 af[4];
#pragma unroll
      for (int i = 0; i < 4; ++i) af[i] = *(const f16x8*)&Asm[c][(i * 16 + r) * 64 + pc];
      const f16x8 bf = *(const f16x8*)&Bsm[c][(wave * 16 + r) * 64 + pc];
#pragma unroll
      for (int i = 0; i < 4; ++i)
        acc[i] = __builtin_amdgcn_mfma_f32_16x16x32_f16(af[i], bf, acc[i], 0, 0, 0);
    }
    if (kt + 1 < 8) writeB(o);  // after compute's ds_reads; different buffer
    __syncthreads();            // drains DMA(kt+1) + writes; swap
  }
  // C/D: row(o)=q*4+g, col(m)=r
  const int m = m0 + wave * 16 + r;
#pragma unroll
  for (int i = 0; i < 4; ++i)
#pragma unroll
    for (int g = 0; g < 4; ++g)
      supT[(size_t)(o0 + i * 16 + q * 4 + g) * N_NODES + m] = (f16)acc[i][g];
}

// -------- gemm2: P16[y][n][o] = sum_{m in slice y} adj[n][m]^2 * supT[o][m] --
// 128n x 256o tile, BK=64, split-K=8. 512 threads (8 waves as 2n x 4o).
// LDS: A double-buffered (2x16 KB) + B single (32 KB) = 64 KB -> 2 blocks/CU
// (16 waves/CU). Structure per kt:
//   loadA(kt+1)                     [adj HBM loads fly across 32 MFMAs]
//   compute(kt)                     [A[cb], Bsm]
//   sync
//   issueB(kt+1) + writeA(->A[ob])  [B DMA is L2-hit; covered by sibling block]
//   sync
// y = wg&7 pins each split-K slice to one XCD (round-robin dispatch) so its
// 512 KB supT slice stays L2-resident against the adj stream.
template <bool ATOMIC>
__global__ __launch_bounds__(512, 4) void gemm2(const float* __restrict__ adj,
                                                const f16* __restrict__ supT,
                                                f16* __restrict__ P16,
                                                float* __restrict__ outp) {
  __shared__ __align__(16) f16 Asm[2][BN2 * 64];  // adj^2 tiles (2 x 16 KB)
  __shared__ __align__(16) f16 Bsm[256 * 64];     // supT tile (32 KB)
  const int t = threadIdx.x;
  const int wave = t >> 6, lane = t & 63;
  const int q = lane >> 4, r = lane & 15;
  const int wn = wave >> 2, wo = wave & 3;  // wave tile: 64n x 64o
  const int wg = blockIdx.x;
  const int y = wg & (SPLITK - 1);
  const int n0 = (wg >> LOG_SPLITK) * BN2;
  const size_t m_base = (size_t)y * MSLICE;

  f32x4 acc[4][4];
#pragma unroll
  for (int i = 0; i < 4; ++i)
#pragma unroll
    for (int j = 0; j < 4; ++j) acc[i][j] = (f32x4){0.f, 0.f, 0.f, 0.f};

  const int a_row = t >> 2;        // 0..127
  const int a_c0 = (t & 3) * 2;
  const float* aptr = adj + (size_t)(n0 + a_row) * N_NODES + m_base + (t & 3) * 16;
  const int b_o8 = lane >> 3;      // row within an 8-row copy group
  const int b_kb = lane & 7;

  f32x4 av[4];

  auto issueB = [&](int kt) {
#pragma unroll
    for (int j = 0; j < 4; ++j) {
      const int c = wave * 4 + j;          // 0..31 -> rows c*8..c*8+7
      const int o = c * 8 + b_o8;
      const int kb = b_kb ^ (o & 7);
      const f16* src = supT + (size_t)o * N_NODES + m_base + kt * 64 + kb * 8;
      async_copy16(&Bsm[c * 8 * 64], src);
    }
  };
  auto loadA = [&](int kt) {
    const float* ap = aptr + kt * 64;
    av[0] = *(const f32x4*)(ap + 0);
    av[1] = *(const f32x4*)(ap + 4);
    av[2] = *(const f32x4*)(ap + 8);
    av[3] = *(const f32x4*)(ap + 12);
  };
  auto writeA = [&](int buf) {
    f16x8 h0, h1;
#pragma unroll
    for (int u = 0; u < 4; ++u) {
      h0[u] = (f16)(av[0][u] * av[0][u]);
      h0[4 + u] = (f16)(av[1][u] * av[1][u]);
      h1[u] = (f16)(av[2][u] * av[2][u]);
      h1[4 + u] = (f16)(av[3][u] * av[3][u]);
    }
    *(f16x8*)&Asm[buf][a_row * 64 + ((a_c0 ^ (a_row & 7)) * 8)] = h0;
    *(f16x8*)&Asm[buf][a_row * 64 + (((a_c0 + 1) ^ (a_row & 7)) * 8)] = h1;
  };

  // prologue: stage kt=0 (A into buf 0, B into the single buffer)
  loadA(0);
  writeA(0);
  issueB(0);
  __syncthreads();

  for (int kt = 0; kt < KT2; ++kt) {
    const int cb = kt & 1, ob = cb ^ 1;
    if (kt + 1 < KT2) loadA(kt + 1);  // adj loads fly across the MFMA phase
#pragma unroll
    for (int s = 0; s < 2; ++s) {
      const int pc = ((s * 4 + q) ^ (r & 7)) * 8;
      f16x8 af[4], bf[4];
#pragma unroll
      for (int i = 0; i < 4; ++i)
        af[i] = *(const f16x8*)&Asm[cb][(wn * 64 + i * 16 + r) * 64 + pc];
#pragma unroll
      for (int j = 0; j < 4; ++j)
        bf[j] = *(const f16x8*)&Bsm[(wo * 64 + j * 16 + r) * 64 + pc];
#pragma unroll
      for (int i = 0; i < 4; ++i)
#pragma unroll
        for (int j = 0; j < 4; ++j)
          acc[i][j] = __builtin_amdgcn_mfma_f32_16x16x32_f16(af[i], bf[j],
                                                             acc[i][j], 0, 0, 0);
    }
    __syncthreads();                 // all waves done reading Bsm / A[cb]
    if (kt + 1 < KT2) {
      issueB(kt + 1);                // supT DMA (L2-hit) into Bsm
      writeA(ob);                    // adj regs (loaded pre-compute) -> A[ob]
    }
    __syncthreads();                 // drain DMA + A writes
  }
  if (ATOMIC) {
#pragma unroll
    for (int i = 0; i < 4; ++i)
#pragma unroll
      for (int g = 0; g < 4; ++g) {
        const int n = n0 + wn * 64 + i * 16 + q * 4 + g;
        float* orow = outp + (size_t)n * OUTF + wo * 64 + r;
#pragma unroll
        for (int j = 0; j < 4; ++j) atomicAdd(orow + j * 16, acc[i][j][g]);
      }
  } else {
    f16* base = P16 + (size_t)y * N_NODES * OUTF;
#pragma unroll
    for (int i = 0; i < 4; ++i)
#pragma unroll
      for (int g = 0; g < 4; ++g) {
        const int n = n0 + wn * 64 + i * 16 + q * 4 + g;
        f16* orow = base + (size_t)n * OUTF + wo * 64 + r;
#pragma unroll
        for (int j = 0; j < 4; ++j) orow[j * 16] = (f16)acc[i][j][g];
      }
  }
}

// -------- epilogue A: sum 8 f16 partial planes + bias + ELU (16B loads) ----
__global__ __launch_bounds__(256) void reduce_elu(const f16* __restrict__ P16,
                                                  const float* __restrict__ bias,
                                                  float* __restrict__ out) {
  const int idx = blockIdx.x * 256 + threadIdx.x;  // f16x8 index, 262144 total
  float s[8];
#pragma unroll
  for (int u = 0; u < 8; ++u) s[u] = 0.f;
#pragma unroll
  for (int y = 0; y < SPLITK; ++y) {
    const f16x8 h = ((const f16x8*)(P16 + (size_t)y * N_NODES * OUTF))[idx];
#pragma unroll
    for (int u = 0; u < 8; ++u) s[u] += (float)h[u];
  }
  const float* bp = bias + (idx & 31) * 8;
  f32x4 v0, v1;
#pragma unroll
  for (int u = 0; u < 4; ++u) {
    v0[u] = elu(s[u] + bp[u]);
    v1[u] = elu(s[4 + u] + bp[4 + u]);
  }
  ((f32x4*)out)[idx * 2 + 0] = v0;
  ((f32x4*)out)[idx * 2 + 1] = v1;
}

// -------- epilogue B (atomic fallback): in-place bias + ELU --------
__global__ __launch_bounds__(256) void bias_elu(float* __restrict__ out,
                                                const float* __restrict__ bias) {
  const int idx = blockIdx.x * 256 + threadIdx.x;
  f32x4 v = ((const f32x4*)out)[idx];
  const f32x4 b = ((const f32x4*)bias)[idx & 63];
#pragma unroll
  for (int u = 0; u < 4; ++u) v[u] = elu(v[u] + b[u]);
  ((f32x4*)out)[idx] = v;
}

extern "C" void kernel_launch(void* const* d_in, const int* in_sizes, int n_in,
                              void* d_out, int out_size, void* d_ws, size_t ws_size,
                              hipStream_t stream) {
  const float* X = (const float*)d_in[0];     // [8192, 512]
  const float* adj = (const float*)d_in[1];   // [8192, 8192]
  const float* W = (const float*)d_in[2];     // [512, 256]
  const float* bias = (const float*)d_in[3];  // [256]
  float* out = (float*)d_out;                 // [8192, 256] fp32

  char* ws = (char*)d_ws;
  f16* supT = (f16*)(ws + 0);           // 4 MB
  f16* WhT = (f16*)(ws + (4u << 20));   // 256 KB
  f16* P16 = (f16*)(ws + (8u << 20));   // 32 MB f16 partials (8 planes)
  const size_t need = (40u << 20);

  prep_w<<<INF * OUTF / 256, 256, 0, stream>>>(W, WhT);
  gemm1<<<dim3(OUTF / 64, N_NODES / 64), 256, 0, stream>>>(WhT, X, supT);
  if (ws_size >= need) {
    gemm2<false><<<dim3((N_NODES / BN2) * SPLITK), dim3(512), 0, stream>>>(adj, supT, P16, nullptr);
    reduce_elu<<<N_NODES * OUTF / 8 / 256, 256, 0, stream>>>(P16, bias, out);
  } else {
    hipMemsetAsync(d_out, 0, (size_t)out_size * sizeof(float), stream);
    gemm2<true><<<dim3((N_NODES / BN2) * SPLITK), dim3(512), 0, stream>>>(adj, supT, nullptr, out);
    bias_elu<<<N_NODES * OUTF / 4 / 256, 256, 0, stream>>>(out, bias);
  }
}